// Round 1
// baseline (232.968 us; speedup 1.0000x reference)
//
#include <hip/hip_runtime.h>

#define BB 64
#define TT 2048
#define EE 1024
#define TCHUNK 256          // t's per k_et block
#define NTCH (TT / TCHUNK)  // 8
#define TSPLIT 16           // k_wsum t splits
#define TS_LEN (TT / TSPLIT) // 128

// ---------------- K1: et[b,t] = b[t] + c[b,:]·U[:,t] + x[b,t,:]·W ----------------
__global__ __launch_bounds__(256) void k_et(const float* __restrict__ x,
                                            const float* __restrict__ c,
                                            const float* __restrict__ W,
                                            const float* __restrict__ bvec,
                                            const float* __restrict__ U,
                                            float* __restrict__ et) {
    // tchunk = blockIdx & 7 so same-U-slice blocks land on the same XCD (L2 reuse)
    const int tch = blockIdx.x & 7;
    const int b   = blockIdx.x >> 3;
    const int t0  = tch * TCHUNK;
    const int tid = threadIdx.x;

    __shared__ float c_s[EE];
    __shared__ float et_s[TCHUNK];

    // stage c[b,:] into LDS (256 threads x float4)
    {
        const float4* cp = (const float4*)(c + (size_t)b * EE);
        ((float4*)c_s)[tid] = cp[tid];
    }
    __syncthreads();

    // Phase A: one t per thread; U[e*T+t] coalesced across threads, c_s broadcast
    {
        const int t = t0 + tid;
        float acc = bvec[t];
        const float* Up = U + t;
        #pragma unroll 16
        for (int e = 0; e < EE; ++e) {
            acc += c_s[e] * Up[(size_t)e * TT];
        }
        et_s[tid] = acc;
    }
    __syncthreads();

    // Phase B: wave-cooperative xw[t] = x[b,t,:]·W  (x read once, coalesced float4)
    {
        const int wave = tid >> 6;
        const int lane = tid & 63;
        // W fragment: lane covers e = 4*lane + 256*k, k=0..3
        float4 wf[4];
        #pragma unroll
        for (int k = 0; k < 4; ++k) wf[k] = ((const float4*)W)[lane + 64 * k];

        const float* xb = x + (size_t)b * TT * EE;
        #pragma unroll 2
        for (int i = 0; i < 64; ++i) {
            const int tl = wave * 64 + i;
            const float4* xr = (const float4*)(xb + (size_t)(t0 + tl) * EE);
            float s = 0.f;
            #pragma unroll
            for (int k = 0; k < 4; ++k) {
                float4 xv = xr[lane + 64 * k];
                s += xv.x * wf[k].x + xv.y * wf[k].y + xv.z * wf[k].z + xv.w * wf[k].w;
            }
            #pragma unroll
            for (int off = 32; off >= 1; off >>= 1)
                s += __shfl_xor(s, off, 64);
            if (lane == 0) et_s[tl] += s;
        }
    }
    __syncthreads();
    et[(size_t)b * TT + t0 + tid] = et_s[tid];
}

// ---------------- K2: row softmax over t ----------------
__global__ __launch_bounds__(256) void k_softmax(float* __restrict__ et) {
    const int b = blockIdx.x;
    float* row = et + (size_t)b * TT;
    const int tid = threadIdx.x;
    const int wave = tid >> 6, lane = tid & 63;

    float v[8];
    float m = -1e30f;
    #pragma unroll
    for (int i = 0; i < 8; ++i) {
        v[i] = row[tid + 256 * i];
        m = fmaxf(m, v[i]);
    }
    __shared__ float redm[4];
    #pragma unroll
    for (int off = 32; off >= 1; off >>= 1) m = fmaxf(m, __shfl_xor(m, off, 64));
    if (lane == 0) redm[wave] = m;
    __syncthreads();
    m = fmaxf(fmaxf(redm[0], redm[1]), fmaxf(redm[2], redm[3]));

    float l = 0.f;
    #pragma unroll
    for (int i = 0; i < 8; ++i) { v[i] = __expf(v[i] - m); l += v[i]; }
    #pragma unroll
    for (int off = 32; off >= 1; off >>= 1) l += __shfl_xor(l, off, 64);
    __shared__ float redl[4];
    if (lane == 0) redl[wave] = l;
    __syncthreads();
    l = redl[0] + redl[1] + redl[2] + redl[3];
    const float inv = 1.f / l;
    #pragma unroll
    for (int i = 0; i < 8; ++i) row[tid + 256 * i] = v[i] * inv;
}

// ---------------- zero d_out ----------------
__global__ void k_zero(float* __restrict__ out, int n) {
    int i = blockIdx.x * 256 + threadIdx.x;
    if (i < n) out[i] = 0.f;
}

// ---------------- K3: out[b,e] += sum_t at[b,t]*x[b,t,e]  (t-split + atomics) ----
__global__ __launch_bounds__(256) void k_wsum(const float* __restrict__ x,
                                              const float* __restrict__ at,
                                              float* __restrict__ out) {
    const int b  = blockIdx.x / TSPLIT;
    const int ts = blockIdx.x % TSPLIT;
    const int t0 = ts * TS_LEN;
    const int tid = threadIdx.x;

    const float* xb = x + (size_t)b * TT * EE;
    const float* ab = at + (size_t)b * TT + t0;

    float4 acc = make_float4(0.f, 0.f, 0.f, 0.f);
    for (int i = 0; i < TS_LEN; ++i) {
        const float a = ab[i];                     // uniform -> scalar load
        const float4 xv = ((const float4*)(xb + (size_t)(t0 + i) * EE))[tid];
        acc.x += a * xv.x; acc.y += a * xv.y;
        acc.z += a * xv.z; acc.w += a * xv.w;
    }
    float* op = out + (size_t)b * EE + tid * 4;
    atomicAdd(op + 0, acc.x);
    atomicAdd(op + 1, acc.y);
    atomicAdd(op + 2, acc.z);
    atomicAdd(op + 3, acc.w);
}

extern "C" void kernel_launch(void* const* d_in, const int* in_sizes, int n_in,
                              void* d_out, int out_size, void* d_ws, size_t ws_size,
                              hipStream_t stream) {
    const float* x    = (const float*)d_in[0];  // (B,T,E)
    const float* c    = (const float*)d_in[1];  // (B,E)
    const float* W    = (const float*)d_in[2];  // (E,1)
    const float* bvec = (const float*)d_in[3];  // (T,1)
    const float* U    = (const float*)d_in[4];  // (E,T)
    float* out = (float*)d_out;                 // (B,E)
    float* et  = (float*)d_ws;                  // B*T floats = 512 KB scratch

    k_et<<<BB * NTCH, 256, 0, stream>>>(x, c, W, bvec, U, et);
    k_softmax<<<BB, 256, 0, stream>>>(et);
    k_zero<<<(BB * EE + 255) / 256, 256, 0, stream>>>(out, BB * EE);
    k_wsum<<<BB * TSPLIT, 256, 0, stream>>>(x, et, out);
}

// Round 2
// 158.540 us; speedup vs baseline: 1.4695x; 1.4695x over previous
//
#include <hip/hip_runtime.h>

#define BB 64
#define TT 2048
#define EE 1024

// k_cu chunking
#define TCHUNK 256
#define NTCH (TT / TCHUNK)   // 8

// flash split
#define ST 32                // t-splits per batch row
#define TBLK (TT / ST)       // 64 t per block
#define TWAVE (TBLK / 4)     // 16 t per wave

// ws layout (float offsets)
#define CU_OFF 0                         // B*T      = 131072
#define M_OFF  (BB * TT)                 // B*ST     = 2048
#define L_OFF  (M_OFF + BB * ST)         // B*ST     = 2048
#define O_OFF  (L_OFF + BB * ST)         // B*ST*EE  = 8388608 (float4-aligned)

// ---------------- K1: cu[b,t] = bvec[t] + c[b,:]·U[:,t] ----------------
__global__ __launch_bounds__(256) void k_cu(const float* __restrict__ c,
                                            const float* __restrict__ bvec,
                                            const float* __restrict__ U,
                                            float* __restrict__ cu) {
    // tchunk = blockIdx & 7 so same-U-slice blocks land on the same XCD (L2 reuse)
    const int tch = blockIdx.x & 7;
    const int b   = blockIdx.x >> 3;
    const int t0  = tch * TCHUNK;
    const int tid = threadIdx.x;

    __shared__ float c_s[EE];
    ((float4*)c_s)[tid] = ((const float4*)(c + (size_t)b * EE))[tid];
    __syncthreads();

    const int t = t0 + tid;
    float acc = bvec[t];
    const float* Up = U + t;
    #pragma unroll 16
    for (int e = 0; e < EE; ++e) {
        acc += c_s[e] * Up[(size_t)e * TT];
    }
    cu[(size_t)b * TT + t] = acc;
}

// ------- K2: single-pass online softmax-weighted sum, partial per (b,ts) -------
// Each wave holds full E across lanes: lane covers e = 4*lane + 256*k (+0..3), k=0..3.
__global__ __launch_bounds__(256, 4) void k_flash(const float* __restrict__ x,
                                                  const float* __restrict__ W,
                                                  const float* __restrict__ cu,
                                                  float* __restrict__ m_part,
                                                  float* __restrict__ l_part,
                                                  float* __restrict__ o_part) {
    const int b   = blockIdx.x / ST;
    const int ts  = blockIdx.x % ST;
    const int tid = threadIdx.x;
    const int wave = tid >> 6, lane = tid & 63;
    const int t0 = ts * TBLK + wave * TWAVE;

    // W fragment (same lane->e mapping as accumulator)
    float4 wf[4];
    #pragma unroll
    for (int k = 0; k < 4; ++k) wf[k] = ((const float4*)W)[lane + 64 * k];

    const float* xb  = x + (size_t)b * TT * EE;
    const float* cub = cu + (size_t)b * TT;

    float m = -1e30f, l = 0.f;
    float4 o[4];
    #pragma unroll
    for (int k = 0; k < 4; ++k) o[k] = make_float4(0.f, 0.f, 0.f, 0.f);

    #pragma unroll 2
    for (int i = 0; i < TWAVE; ++i) {
        const int t = t0 + i;
        const float4* xr = (const float4*)(xb + (size_t)t * EE);
        float4 xv[4];
        #pragma unroll
        for (int k = 0; k < 4; ++k) xv[k] = xr[lane + 64 * k];

        float s = 0.f;
        #pragma unroll
        for (int k = 0; k < 4; ++k)
            s += xv[k].x * wf[k].x + xv[k].y * wf[k].y +
                 xv[k].z * wf[k].z + xv[k].w * wf[k].w;
        #pragma unroll
        for (int off = 32; off >= 1; off >>= 1)
            s += __shfl_xor(s, off, 64);
        const float et = s + cub[t];          // wave-uniform

        if (et > m) {                         // uniform branch, no divergence
            const float r = __expf(m - et);
            l *= r;
            #pragma unroll
            for (int k = 0; k < 4; ++k) {
                o[k].x *= r; o[k].y *= r; o[k].z *= r; o[k].w *= r;
            }
            m = et;
        }
        const float p = __expf(et - m);
        l += p;
        #pragma unroll
        for (int k = 0; k < 4; ++k) {
            o[k].x += p * xv[k].x; o[k].y += p * xv[k].y;
            o[k].z += p * xv[k].z; o[k].w += p * xv[k].w;
        }
    }

    // ---- block merge of 4 wave partials via LDS ----
    __shared__ float m_s[4], l_s[4];
    __shared__ float o_s[4][EE];
    if (lane == 0) { m_s[wave] = m; l_s[wave] = l; }
    __syncthreads();
    const float M = fmaxf(fmaxf(m_s[0], m_s[1]), fmaxf(m_s[2], m_s[3]));
    const float r = __expf(m - M);
    float4* osw = (float4*)o_s[wave];
    #pragma unroll
    for (int k = 0; k < 4; ++k) {
        float4 t = o[k];
        t.x *= r; t.y *= r; t.z *= r; t.w *= r;
        osw[lane + 64 * k] = t;
    }
    __syncthreads();

    const int pi = b * ST + ts;
    float4 acc = make_float4(0.f, 0.f, 0.f, 0.f);
    #pragma unroll
    for (int w = 0; w < 4; ++w) {
        const float4 v = ((const float4*)o_s[w])[tid];
        acc.x += v.x; acc.y += v.y; acc.z += v.z; acc.w += v.w;
    }
    ((float4*)(o_part + (size_t)pi * EE))[tid] = acc;
    if (tid == 0) {
        float L = 0.f;
        #pragma unroll
        for (int w = 0; w < 4; ++w) L += __expf(m_s[w] - M) * l_s[w];
        m_part[pi] = M;
        l_part[pi] = L;
    }
}

// ---------------- K3: merge ST partials per batch row ----------------
__global__ __launch_bounds__(256) void k_merge(const float* __restrict__ m_part,
                                               const float* __restrict__ l_part,
                                               const float* __restrict__ o_part,
                                               float* __restrict__ out) {
    const int b = blockIdx.x;
    const int tid = threadIdx.x;

    float M = -1e30f;
    #pragma unroll 8
    for (int ts = 0; ts < ST; ++ts) M = fmaxf(M, m_part[b * ST + ts]);

    float L = 0.f;
    float4 acc = make_float4(0.f, 0.f, 0.f, 0.f);
    for (int ts = 0; ts < ST; ++ts) {
        const int pi = b * ST + ts;
        const float r = __expf(m_part[pi] - M);
        L += r * l_part[pi];
        const float4 v = ((const float4*)(o_part + (size_t)pi * EE))[tid];
        acc.x += r * v.x; acc.y += r * v.y; acc.z += r * v.z; acc.w += r * v.w;
    }
    const float inv = 1.f / L;
    acc.x *= inv; acc.y *= inv; acc.z *= inv; acc.w *= inv;
    ((float4*)(out + (size_t)b * EE))[tid] = acc;
}

extern "C" void kernel_launch(void* const* d_in, const int* in_sizes, int n_in,
                              void* d_out, int out_size, void* d_ws, size_t ws_size,
                              hipStream_t stream) {
    const float* x    = (const float*)d_in[0];  // (B,T,E)
    const float* c    = (const float*)d_in[1];  // (B,E)
    const float* W    = (const float*)d_in[2];  // (E,1)
    const float* bvec = (const float*)d_in[3];  // (T,1)
    const float* U    = (const float*)d_in[4];  // (E,T)
    float* out = (float*)d_out;                 // (B,E)

    float* ws     = (float*)d_ws;
    float* cu     = ws + CU_OFF;
    float* m_part = ws + M_OFF;
    float* l_part = ws + L_OFF;
    float* o_part = ws + O_OFF;

    k_cu<<<BB * NTCH, 256, 0, stream>>>(c, bvec, U, cu);
    k_flash<<<BB * ST, 256, 0, stream>>>(x, W, cu, m_part, l_part, o_part);
    k_merge<<<BB, 256, 0, stream>>>(m_part, l_part, o_part, out);
}

// Round 3
// 139.157 us; speedup vs baseline: 1.6741x; 1.1393x over previous
//
#include <hip/hip_runtime.h>
#include <stdint.h>

#define BB 64
#define TT 2048
#define EE 1024
#define ST 32
#define TBLK (TT / ST)      // 64 rows per block
#define CHUNK 4             // rows per staged chunk
#define NCH (TBLK / CHUNK)  // 16 chunks

// ws float offsets
#define M_OFF 0
#define L_OFF (BB * ST)
#define O_OFF (2 * BB * ST)

__device__ __forceinline__ void gload16(const float* g, float* l) {
    __builtin_amdgcn_global_load_lds((const __attribute__((address_space(1))) void*)g,
                                     (__attribute__((address_space(3))) void*)l,
                                     16, 0, 0);
}

// One fused pass: et = c·U + x·W + b computed on the fly, online softmax,
// weighted-sum accumulation. Partial (m,l,o) per (b,ts) block.
__global__ __launch_bounds__(256) void k_fused(
    const float* __restrict__ x, const float* __restrict__ c,
    const float* __restrict__ W, const float* __restrict__ bvec,
    const float* __restrict__ U,
    float* __restrict__ m_part, float* __restrict__ l_part,
    float* __restrict__ o_part)
{
    const int b    = blockIdx.x >> 5;   // blockIdx = b*ST + ts
    const int ts   = blockIdx.x & 31;
    const int tid  = threadIdx.x;
    const int w    = tid >> 6;          // wave id: owns e-quarter [256w, 256w+256)
    const int lane = tid & 63;
    const int t0   = ts * TBLK;

    __shared__ float  xs[3][CHUNK * EE];   // 48 KB triple-buffered x rows
    __shared__ float  cu_s[TBLK];
    __shared__ float  pcu[4][TBLK];
    __shared__ float4 p_s[4];              // per-wave partial dots (4 rows)

    const float* xb = x + ((size_t)b * TT + t0) * EE;

    // ---- issue async stages for chunks 0,1 (overlap with U-dot prologue) ----
    {
        const float* s0 = xb + (size_t)(0 * CHUNK + w) * EE + lane * 4;
        const float* s1 = xb + (size_t)(1 * CHUNK + w) * EE + lane * 4;
        float* d0 = &xs[0][w * EE];
        float* d1 = &xs[1][w * EE];
        #pragma unroll
        for (int seg = 0; seg < 4; ++seg) gload16(s0 + seg * 256, d0 + seg * 256);
        #pragma unroll
        for (int seg = 0; seg < 4; ++seg) gload16(s1 + seg * 256, d1 + seg * 256);
    }

    // ---- prologue: cu_s[t] = bvec[t0+t] + c[b,:]·U[:,t0+t] ----
    // wave w covers e-quarter w; lane = local t. U reads coalesced (256B/instr),
    // c reads wave-uniform -> scalar loads. Same-ts blocks share the U slice on
    // one XCD (blockIdx ≡ ts mod 8) -> L2-resident re-reads.
    {
        const float* cb = c + (size_t)b * EE + (w << 8);
        const float* Ub = U + (size_t)(w << 8) * TT + t0 + lane;
        float a0 = 0.f, a1 = 0.f, a2 = 0.f, a3 = 0.f;
        #pragma unroll 4
        for (int e = 0; e < 256; e += 4) {
            a0 = fmaf(cb[e + 0], Ub[(size_t)(e + 0) * TT], a0);
            a1 = fmaf(cb[e + 1], Ub[(size_t)(e + 1) * TT], a1);
            a2 = fmaf(cb[e + 2], Ub[(size_t)(e + 2) * TT], a2);
            a3 = fmaf(cb[e + 3], Ub[(size_t)(e + 3) * TT], a3);
        }
        pcu[w][lane] = (a0 + a1) + (a2 + a3);
    }
    __syncthreads();   // drains vmcnt too: chunks 0,1 staged by loop entry
    if (tid < TBLK)
        cu_s[tid] = bvec[t0 + tid] + pcu[0][tid] + pcu[1][tid] + pcu[2][tid] + pcu[3][tid];
    __syncthreads();

    const float4 wf = ((const float4*)W)[(w << 6) + lane];

    float  m = -1e30f, l = 0.f;
    float4 o = make_float4(0.f, 0.f, 0.f, 0.f);

    for (int ch = 0; ch < NCH; ++ch) {
        // wait for own stage(ch) loads (counted: stage(ch+1) stays in flight)
        if (ch < NCH - 1) asm volatile("s_waitcnt vmcnt(4)" ::: "memory");
        else              asm volatile("s_waitcnt vmcnt(0)" ::: "memory");
        __builtin_amdgcn_s_barrier();        // all waves' stage(ch) complete;
        asm volatile("" ::: "memory");       // also: all done computing ch-1

        // prefetch ch+2 into the buffer freed by ch-1
        if (ch + 2 < NCH) {
            const float* sr = xb + (size_t)((ch + 2) * CHUNK + w) * EE + lane * 4;
            float* d = &xs[(ch + 2) % 3][w * EE];
            #pragma unroll
            for (int seg = 0; seg < 4; ++seg) gload16(sr + seg * 256, d + seg * 256);
        }

        // quarter-row dots for the 4 rows of this chunk
        const float4* bp = (const float4*)xs[ch % 3];
        float4 xv0 = bp[0 * 256 + (w << 6) + lane];
        float4 xv1 = bp[1 * 256 + (w << 6) + lane];
        float4 xv2 = bp[2 * 256 + (w << 6) + lane];
        float4 xv3 = bp[3 * 256 + (w << 6) + lane];
        float s0 = xv0.x * wf.x + xv0.y * wf.y + xv0.z * wf.z + xv0.w * wf.w;
        float s1 = xv1.x * wf.x + xv1.y * wf.y + xv1.z * wf.z + xv1.w * wf.w;
        float s2 = xv2.x * wf.x + xv2.y * wf.y + xv2.z * wf.z + xv2.w * wf.w;
        float s3 = xv3.x * wf.x + xv3.y * wf.y + xv3.z * wf.z + xv3.w * wf.w;
        #pragma unroll
        for (int off = 32; off >= 1; off >>= 1) {   // 4 independent chains
            s0 += __shfl_xor(s0, off, 64);
            s1 += __shfl_xor(s1, off, 64);
            s2 += __shfl_xor(s2, off, 64);
            s3 += __shfl_xor(s3, off, 64);
        }
        if (lane == 0) p_s[w] = make_float4(s0, s1, s2, s3);
        asm volatile("s_waitcnt lgkmcnt(0)" ::: "memory");
        __builtin_amdgcn_s_barrier();        // partials visible
        asm volatile("" ::: "memory");

        const float4 q0 = p_s[0], q1 = p_s[1], q2 = p_s[2], q3 = p_s[3];
        const int cb4 = ch * CHUNK;
        const float et0 = q0.x + q1.x + q2.x + q3.x + cu_s[cb4 + 0];
        const float et1 = q0.y + q1.y + q2.y + q3.y + cu_s[cb4 + 1];
        const float et2 = q0.z + q1.z + q2.z + q3.z + cu_s[cb4 + 2];
        const float et3 = q0.w + q1.w + q2.w + q3.w + cu_s[cb4 + 3];

        // branch-free online-softmax update (register-only; xv held from dot)
        const float mn = fmaxf(fmaxf(m, fmaxf(et0, et1)), fmaxf(et2, et3));
        const float r  = __expf(m - mn);
        const float p0 = __expf(et0 - mn);
        const float p1 = __expf(et1 - mn);
        const float p2 = __expf(et2 - mn);
        const float p3 = __expf(et3 - mn);
        l = l * r + ((p0 + p1) + (p2 + p3));
        o.x = o.x * r + p0 * xv0.x + p1 * xv1.x + p2 * xv2.x + p3 * xv3.x;
        o.y = o.y * r + p0 * xv0.y + p1 * xv1.y + p2 * xv2.y + p3 * xv3.y;
        o.z = o.z * r + p0 * xv0.z + p1 * xv1.z + p2 * xv2.z + p3 * xv3.z;
        o.w = o.w * r + p0 * xv0.w + p1 * xv1.w + p2 * xv2.w + p3 * xv3.w;
        m = mn;
    }

    // waves own disjoint e-quarters: direct coalesced partial write
    const int pi = blockIdx.x;
    ((float4*)o_part)[(size_t)pi * 256 + (w << 6) + lane] = o;
    if (tid == 0) { m_part[pi] = m; l_part[pi] = l; }
}

// ---------------- merge ST partials per batch row ----------------
__global__ __launch_bounds__(256) void k_merge(const float* __restrict__ m_part,
                                               const float* __restrict__ l_part,
                                               const float* __restrict__ o_part,
                                               float* __restrict__ out) {
    const int b = blockIdx.x;
    const int tid = threadIdx.x;

    float M = -1e30f;
    #pragma unroll 8
    for (int ts = 0; ts < ST; ++ts) M = fmaxf(M, m_part[b * ST + ts]);

    float L = 0.f;
    float4 acc = make_float4(0.f, 0.f, 0.f, 0.f);
    for (int ts = 0; ts < ST; ++ts) {
        const int pi = b * ST + ts;
        const float r = __expf(m_part[pi] - M);
        L += r * l_part[pi];
        const float4 v = ((const float4*)(o_part + (size_t)pi * EE))[tid];
        acc.x += r * v.x; acc.y += r * v.y; acc.z += r * v.z; acc.w += r * v.w;
    }
    const float inv = 1.f / L;
    acc.x *= inv; acc.y *= inv; acc.z *= inv; acc.w *= inv;
    ((float4*)(out + (size_t)b * EE))[tid] = acc;
}

extern "C" void kernel_launch(void* const* d_in, const int* in_sizes, int n_in,
                              void* d_out, int out_size, void* d_ws, size_t ws_size,
                              hipStream_t stream) {
    const float* x    = (const float*)d_in[0];  // (B,T,E)
    const float* c    = (const float*)d_in[1];  // (B,E)
    const float* W    = (const float*)d_in[2];  // (E,1)
    const float* bvec = (const float*)d_in[3];  // (T,1)
    const float* U    = (const float*)d_in[4];  // (E,T)
    float* out = (float*)d_out;                 // (B,E)

    float* ws     = (float*)d_ws;
    float* m_part = ws + M_OFF;
    float* l_part = ws + L_OFF;
    float* o_part = ws + O_OFF;

    k_fused<<<BB * ST, 256, 0, stream>>>(x, c, W, bvec, U, m_part, l_part, o_part);
    k_merge<<<BB, 256, 0, stream>>>(m_part, l_part, o_part, out);
}

// Round 4
// 136.319 us; speedup vs baseline: 1.7090x; 1.0208x over previous
//
#include <hip/hip_runtime.h>
#include <stdint.h>

#define BB 64
#define TT 2048
#define EE 1024
#define ST 32                 // t-splits per batch row
#define TBLK (TT / ST)        // 64 t per (b,ts)
#define BG 4                  // b's per block
#define NBG (BB / BG)         // 16 b-groups
#define RPP 8                 // rows per phase (8 x 4KB = 32KB stage)
#define NPH (BG * TBLK / RPP) // 32 phases per block

// ws float offsets
#define M_OFF 0
#define L_OFF (BB * ST)
#define O_OFF (2 * BB * ST)

__device__ __forceinline__ void gload16(const float* g, float* l) {
    __builtin_amdgcn_global_load_lds((const __attribute__((address_space(1))) void*)g,
                                     (__attribute__((address_space(3))) void*)l,
                                     16, 0, 0);
}

// Fused single-pass: et = c·U + x·W + b on the fly, online softmax, weighted sum.
// Block = (b-group of 4, ts). Streams 256 rows (1 MB) of x via double-buffered
// global_load_lds, 8-row phases, 2 barriers/phase, counted vmcnt.
__global__ __launch_bounds__(256, 2) void k_fused(
    const float* __restrict__ x, const float* __restrict__ c,
    const float* __restrict__ W, const float* __restrict__ bvec,
    const float* __restrict__ U,
    float* __restrict__ m_part, float* __restrict__ l_part,
    float* __restrict__ o_part)
{
    const int bg   = blockIdx.x >> 5;    // blockIdx = bg*ST + ts  (mod 8 == ts mod 8 -> XCD shares U slice)
    const int ts   = blockIdx.x & 31;
    const int b0   = bg * BG;
    const int t0   = ts * TBLK;
    const int tid  = threadIdx.x;
    const int wu   = __builtin_amdgcn_readfirstlane(tid >> 6);  // wave id (uniform -> scalar addressing)
    const int lane = tid & 63;

    __shared__ float xs[2][RPP * EE];    // 64 KB double-buffered x rows
    __shared__ float cu_s[BG][TBLK];     // 1 KB
    __shared__ float pcu[4][BG][TBLK];   // 4 KB prologue exchange
    __shared__ float p_s[4][RPP];        // per-wave quarter-dot sums

    // ---- issue stage(0): rows 0..7 (b_local 0, t_local 0..7); wave stages 2 rows ----
    {
        const float* src = x + ((size_t)b0 * TT + t0 + 2 * wu) * EE + lane * 4;
        float* d = &xs[0][(2 * wu) * EE];
        #pragma unroll
        for (int r = 0; r < 2; ++r)
            #pragma unroll
            for (int seg = 0; seg < 4; ++seg)
                gload16(src + r * EE + seg * 256, d + r * EE + seg * 256);
    }

    // ---- prologue: cu_s[j][t] = bvec[t0+t] + c[b0+j,:]·U[:,t0+t] for 4 b's ----
    // wave wu covers e in [wu*256, wu*256+256); lane = t. U loaded once, reused x4.
    {
        const float* cb = c + (size_t)b0 * EE + (wu << 8);            // uniform -> s_load
        const float* Ub = U + ((size_t)(wu << 8)) * TT + t0 + lane;   // coalesced 256B
        float a0 = 0.f, a1 = 0.f, a2 = 0.f, a3 = 0.f;
        #pragma unroll 8
        for (int e = 0; e < 256; ++e) {
            const float u = Ub[(size_t)e * TT];
            a0 = fmaf(cb[e], u, a0);
            a1 = fmaf(cb[EE + e], u, a1);
            a2 = fmaf(cb[2 * EE + e], u, a2);
            a3 = fmaf(cb[3 * EE + e], u, a3);
        }
        pcu[wu][0][lane] = a0;
        pcu[wu][1][lane] = a1;
        pcu[wu][2][lane] = a2;
        pcu[wu][3][lane] = a3;
    }
    __syncthreads();
    {
        const int j = tid >> 6, t = tid & 63;
        cu_s[j][t] = bvec[t0 + t] + pcu[0][j][t] + pcu[1][j][t] + pcu[2][j][t] + pcu[3][j][t];
    }
    __syncthreads();   // cu_s visible (writer lgkm-drained + barrier)

    const float4 wf = ((const float4*)W)[(wu << 6) + lane];
    float  m = -1e30f, l = 0.f;
    float4 o = make_float4(0.f, 0.f, 0.f, 0.f);

    for (int ph = 0; ph < NPH; ++ph) {
        const int bl = ph >> 3;

        // issue stage(ph+1) into the buffer all waves finished reading at barrier_B(ph-1)
        if (ph + 1 < NPH) {
            const int bl1 = (ph + 1) >> 3;
            const int tl1 = ((ph + 1) & 7) * 8;
            const float* src = x + ((size_t)(b0 + bl1) * TT + t0 + tl1 + 2 * wu) * EE + lane * 4;
            float* d = &xs[(ph + 1) & 1][(2 * wu) * EE];
            #pragma unroll
            for (int r = 0; r < 2; ++r)
                #pragma unroll
                for (int seg = 0; seg < 4; ++seg)
                    gload16(src + r * EE + seg * 256, d + r * EE + seg * 256);
            asm volatile("s_waitcnt vmcnt(8)" ::: "memory");  // own stage(ph) done; stage(ph+1) in flight
        } else {
            asm volatile("s_waitcnt vmcnt(0)" ::: "memory");
        }
        __builtin_amdgcn_s_barrier();        // barrier_A: everyone's stage(ph) complete
        asm volatile("" ::: "memory");

        // ---- dot phase: e-quarter of 8 rows; 8 interleaved butterfly chains ----
        const float4* bp = (const float4*)xs[ph & 1];
        float4 xv[8];
        float  s[8];
        #pragma unroll
        for (int r = 0; r < 8; ++r) xv[r] = bp[r * 256 + (wu << 6) + lane];
        #pragma unroll
        for (int r = 0; r < 8; ++r)
            s[r] = xv[r].x * wf.x + xv[r].y * wf.y + xv[r].z * wf.z + xv[r].w * wf.w;
        #pragma unroll
        for (int off = 32; off >= 1; off >>= 1) {
            #pragma unroll
            for (int r = 0; r < 8; ++r) s[r] += __shfl_xor(s[r], off, 64);
        }
        if (lane == 0) {
            ((float4*)p_s[wu])[0] = make_float4(s[0], s[1], s[2], s[3]);
            ((float4*)p_s[wu])[1] = make_float4(s[4], s[5], s[6], s[7]);
        }
        asm volatile("s_waitcnt lgkmcnt(0)" ::: "memory");
        __builtin_amdgcn_s_barrier();        // barrier_B: partial sums visible
        asm volatile("" ::: "memory");

        // ---- batched 8-row online-softmax update (register-only; xv held) ----
        const int tl = (ph & 7) * 8;
        const float4 qa0 = ((const float4*)p_s[0])[0], qb0 = ((const float4*)p_s[0])[1];
        const float4 qa1 = ((const float4*)p_s[1])[0], qb1 = ((const float4*)p_s[1])[1];
        const float4 qa2 = ((const float4*)p_s[2])[0], qb2 = ((const float4*)p_s[2])[1];
        const float4 qa3 = ((const float4*)p_s[3])[0], qb3 = ((const float4*)p_s[3])[1];
        const float4 cua = ((const float4*)&cu_s[bl][tl])[0];
        const float4 cub = ((const float4*)&cu_s[bl][tl])[1];
        float et[8];
        et[0] = (qa0.x + qa1.x) + (qa2.x + qa3.x) + cua.x;
        et[1] = (qa0.y + qa1.y) + (qa2.y + qa3.y) + cua.y;
        et[2] = (qa0.z + qa1.z) + (qa2.z + qa3.z) + cua.z;
        et[3] = (qa0.w + qa1.w) + (qa2.w + qa3.w) + cua.w;
        et[4] = (qb0.x + qb1.x) + (qb2.x + qb3.x) + cub.x;
        et[5] = (qb0.y + qb1.y) + (qb2.y + qb3.y) + cub.y;
        et[6] = (qb0.z + qb1.z) + (qb2.z + qb3.z) + cub.z;
        et[7] = (qb0.w + qb1.w) + (qb2.w + qb3.w) + cub.w;

        float mn = m;
        #pragma unroll
        for (int r = 0; r < 8; ++r) mn = fmaxf(mn, et[r]);
        const float rr = __expf(m - mn);
        float p[8];
        #pragma unroll
        for (int r = 0; r < 8; ++r) p[r] = __expf(et[r] - mn);
        l = l * rr + (((p[0] + p[1]) + (p[2] + p[3])) + ((p[4] + p[5]) + (p[6] + p[7])));
        float ax = o.x * rr, ay = o.y * rr, az = o.z * rr, aw = o.w * rr;
        #pragma unroll
        for (int r = 0; r < 8; ++r) {
            ax = fmaf(p[r], xv[r].x, ax);
            ay = fmaf(p[r], xv[r].y, ay);
            az = fmaf(p[r], xv[r].z, az);
            aw = fmaf(p[r], xv[r].w, aw);
        }
        o = make_float4(ax, ay, az, aw);
        m = mn;

        if ((ph & 7) == 7) {               // b-boundary: emit partial, reset state
            const int pi = (b0 + bl) * ST + ts;
            ((float4*)o_part)[(size_t)pi * 256 + (wu << 6) + lane] = o;
            if (tid == 0) { m_part[pi] = m; l_part[pi] = l; }
            m = -1e30f; l = 0.f;
            o = make_float4(0.f, 0.f, 0.f, 0.f);
        }
    }
}

// ---------------- merge ST partials per batch row ----------------
__global__ __launch_bounds__(256) void k_merge(const float* __restrict__ m_part,
                                               const float* __restrict__ l_part,
                                               const float* __restrict__ o_part,
                                               float* __restrict__ out) {
    const int b = blockIdx.x;
    const int tid = threadIdx.x;

    float M = -1e30f;
    #pragma unroll 8
    for (int ts = 0; ts < ST; ++ts) M = fmaxf(M, m_part[b * ST + ts]);

    float L = 0.f;
    float4 acc = make_float4(0.f, 0.f, 0.f, 0.f);
    for (int ts = 0; ts < ST; ++ts) {
        const int pi = b * ST + ts;
        const float r = __expf(m_part[pi] - M);
        L += r * l_part[pi];
        const float4 v = ((const float4*)(o_part + (size_t)pi * EE))[tid];
        acc.x += r * v.x; acc.y += r * v.y; acc.z += r * v.z; acc.w += r * v.w;
    }
    const float inv = 1.f / L;
    acc.x *= inv; acc.y *= inv; acc.z *= inv; acc.w *= inv;
    ((float4*)(out + (size_t)b * EE))[tid] = acc;
}

extern "C" void kernel_launch(void* const* d_in, const int* in_sizes, int n_in,
                              void* d_out, int out_size, void* d_ws, size_t ws_size,
                              hipStream_t stream) {
    const float* x    = (const float*)d_in[0];  // (B,T,E)
    const float* c    = (const float*)d_in[1];  // (B,E)
    const float* W    = (const float*)d_in[2];  // (E,1)
    const float* bvec = (const float*)d_in[3];  // (T,1)
    const float* U    = (const float*)d_in[4];  // (E,T)
    float* out = (float*)d_out;                 // (B,E)

    float* ws     = (float*)d_ws;
    float* m_part = ws + M_OFF;
    float* l_part = ws + L_OFF;
    float* o_part = ws + O_OFF;

    k_fused<<<NBG * ST, 256, 0, stream>>>(x, c, W, bvec, U, m_part, l_part, o_part);
    k_merge<<<BB, 256, 0, stream>>>(m_part, l_part, o_part, out);
}

// Round 5
// 135.201 us; speedup vs baseline: 1.7231x; 1.0083x over previous
//
#include <hip/hip_runtime.h>
#include <stdint.h>

#define BB 64
#define TT 2048
#define EE 1024
#define ST 32                 // t-splits per batch row
#define TBLK (TT / ST)        // 64 t per (b,ts)
#define BG 4                  // b's per block (U-slice reuse x4)
#define NBG (BB / BG)         // 16 b-groups
#define RPP 8                 // rows per phase
#define NPH (BG * TBLK / RPP) // 32 phases per block

// ws float offsets
#define M_OFF 0
#define L_OFF (BB * ST)
#define O_OFF (2 * BB * ST)

// One phase: issue next 8 rows into NXT regs, dot CUR rows vs wf, folded
// 17-shfl reduce (quarter-sums land in lane-group g = row g), tiny LDS
// exchange across waves (1 barrier), batched 8-row online-softmax update.
#define PHASE(ph, CUR, NXT)                                                    \
  do {                                                                         \
    if ((ph) + 1 < NPH) {                                                      \
      const int bl1 = ((ph) + 1) >> 3, tl1 = (((ph) + 1) & 7) * RPP;           \
      const float4* srcp = xq + ((size_t)bl1 * TT + tl1) * 256;                \
      _Pragma("unroll")                                                        \
      for (int r = 0; r < 8; ++r) NXT[r] = srcp[(size_t)r * 256];              \
    }                                                                          \
    float s_[8];                                                               \
    _Pragma("unroll")                                                          \
    for (int r = 0; r < 8; ++r)                                                \
      s_[r] = CUR[r].x * wf.x + CUR[r].y * wf.y +                              \
              CUR[r].z * wf.z + CUR[r].w * wf.w;                               \
    float t_[4];                                                               \
    _Pragma("unroll")                                                          \
    for (int r = 0; r < 4; ++r) {                                              \
      const float ar = s_[r]     + __shfl_xor(s_[r],     32, 64);              \
      const float br = s_[r + 4] + __shfl_xor(s_[r + 4], 32, 64);              \
      t_[r] = (lane < 32) ? ar : br;                                           \
    }                                                                          \
    float u_[2];                                                               \
    _Pragma("unroll")                                                          \
    for (int r = 0; r < 2; ++r) {                                              \
      const float ar = t_[r]     + __shfl_xor(t_[r],     16, 64);              \
      const float br = t_[r + 2] + __shfl_xor(t_[r + 2], 16, 64);              \
      u_[r] = ((lane & 16) == 0) ? ar : br;                                    \
    }                                                                          \
    {                                                                          \
      const float va = u_[0] + __shfl_xor(u_[0], 8, 64);                       \
      const float vb = u_[1] + __shfl_xor(u_[1], 8, 64);                       \
      float v_ = ((lane & 8) == 0) ? va : vb;                                  \
      v_ += __shfl_xor(v_, 4, 64);                                             \
      v_ += __shfl_xor(v_, 2, 64);                                             \
      v_ += __shfl_xor(v_, 1, 64);                                             \
      if ((lane & 7) == 0) ex[(ph) & 1][g][wu] = v_;   /* group g holds row g */ \
    }                                                                          \
    asm volatile("s_waitcnt lgkmcnt(0)" ::: "memory");                         \
    __builtin_amdgcn_s_barrier();                                              \
    asm volatile("" ::: "memory");                                             \
    const int bl_ = (ph) >> 3, tl_ = ((ph) & 7) * RPP;                         \
    const float4 cua = *(const float4*)&cu_s[bl_][tl_];                        \
    const float4 cub = *(const float4*)&cu_s[bl_][tl_ + 4];                    \
    float et[8];                                                               \
    _Pragma("unroll")                                                          \
    for (int r = 0; r < 8; ++r) {                                              \
      const float4 q = ((const float4*)ex[(ph) & 1])[r];  /* broadcast read */ \
      et[r] = (q.x + q.y) + (q.z + q.w);                                       \
    }                                                                          \
    et[0] += cua.x; et[1] += cua.y; et[2] += cua.z; et[3] += cua.w;            \
    et[4] += cub.x; et[5] += cub.y; et[6] += cub.z; et[7] += cub.w;            \
    float mn = m;                                                              \
    _Pragma("unroll")                                                          \
    for (int r = 0; r < 8; ++r) mn = fmaxf(mn, et[r]);                         \
    const float rr = __expf(m - mn);                                           \
    float p_[8];                                                               \
    _Pragma("unroll")                                                          \
    for (int r = 0; r < 8; ++r) p_[r] = __expf(et[r] - mn);                    \
    l = l * rr + (((p_[0] + p_[1]) + (p_[2] + p_[3])) +                        \
                  ((p_[4] + p_[5]) + (p_[6] + p_[7])));                        \
    float ax = o.x * rr, ay = o.y * rr, az = o.z * rr, aw = o.w * rr;          \
    _Pragma("unroll")                                                          \
    for (int r = 0; r < 8; ++r) {                                              \
      ax = fmaf(p_[r], CUR[r].x, ax); ay = fmaf(p_[r], CUR[r].y, ay);          \
      az = fmaf(p_[r], CUR[r].z, az); aw = fmaf(p_[r], CUR[r].w, aw);          \
    }                                                                          \
    o = make_float4(ax, ay, az, aw);                                           \
    m = mn;                                                                    \
    if (((ph) & 7) == 7) {                                                     \
      const int pi = (b0 + bl_) * ST + ts;                                     \
      ((float4*)o_part)[(size_t)pi * 256 + (wu << 6) + lane] = o;              \
      if (tid == 0) { m_part[pi] = m; l_part[pi] = l; }                        \
      m = -1e30f; l = 0.f; o = make_float4(0.f, 0.f, 0.f, 0.f);                \
    }                                                                          \
  } while (0)

// Fused single-pass: et = c·U + x·W + b on the fly, online softmax, weighted
// sum. x streams global->registers directly (no LDS staging), double-buffered
// register sets, one raw s_barrier per 8-row phase for the tiny dot exchange.
__global__ __launch_bounds__(256, 2) void k_fused(
    const float* __restrict__ x, const float* __restrict__ c,
    const float* __restrict__ W, const float* __restrict__ bvec,
    const float* __restrict__ U,
    float* __restrict__ m_part, float* __restrict__ l_part,
    float* __restrict__ o_part)
{
    const int bg   = blockIdx.x >> 5;   // blockIdx = bg*ST + ts (ts mod 8 -> XCD shares U slice)
    const int ts   = blockIdx.x & 31;
    const int b0   = bg * BG;
    const int t0   = ts * TBLK;
    const int tid  = threadIdx.x;
    const int wu   = __builtin_amdgcn_readfirstlane(tid >> 6);  // wave id, uniform
    const int lane = tid & 63;
    const int g    = lane >> 3;

    __shared__ float cu_s[BG][TBLK];    // 1 KB
    __shared__ float pcu[4][BG][TBLK];  // 4 KB prologue exchange
    __shared__ float ex[2][8][4];       // 256 B double-buffered dot exchange

    // lane's x column: e-quarter wu, float4 index (wu<<6)+lane within each row
    const float4* xq = (const float4*)x + ((size_t)b0 * TT + t0) * 256 + (wu << 6) + lane;

    float4 XA[8], XB[8];
    #pragma unroll
    for (int r = 0; r < 8; ++r) XA[r] = xq[(size_t)r * 256];   // phase-0 rows in flight

    // ---- prologue: cu_s[j][t] = bvec[t0+t] + c[b0+j,:]·U[:,t0+t], 4 b's ----
    {
        const float* cb = c + (size_t)b0 * EE + (wu << 8);          // uniform -> s_load
        const float* Ub = U + ((size_t)(wu << 8)) * TT + t0 + lane; // coalesced 256B
        float a0 = 0.f, a1 = 0.f, a2 = 0.f, a3 = 0.f;
        #pragma unroll 8
        for (int e = 0; e < 256; ++e) {
            const float u = Ub[(size_t)e * TT];
            a0 = fmaf(cb[e], u, a0);
            a1 = fmaf(cb[EE + e], u, a1);
            a2 = fmaf(cb[2 * EE + e], u, a2);
            a3 = fmaf(cb[3 * EE + e], u, a3);
        }
        pcu[wu][0][lane] = a0;
        pcu[wu][1][lane] = a1;
        pcu[wu][2][lane] = a2;
        pcu[wu][3][lane] = a3;
    }
    __syncthreads();
    {
        const int j = tid >> 6, t = tid & 63;
        cu_s[j][t] = bvec[t0 + t] + pcu[0][j][t] + pcu[1][j][t] + pcu[2][j][t] + pcu[3][j][t];
    }
    __syncthreads();

    const float4 wf = ((const float4*)W)[(wu << 6) + lane];
    float  m = -1e30f, l = 0.f;
    float4 o = make_float4(0.f, 0.f, 0.f, 0.f);

    for (int ph = 0; ph < NPH; ph += 2) {
        PHASE(ph,     XA, XB);
        PHASE(ph + 1, XB, XA);
    }
}

// ---------------- merge ST partials per batch row ----------------
__global__ __launch_bounds__(256) void k_merge(const float* __restrict__ m_part,
                                               const float* __restrict__ l_part,
                                               const float* __restrict__ o_part,
                                               float* __restrict__ out) {
    const int b = blockIdx.x;
    const int tid = threadIdx.x;

    float M = -1e30f;
    #pragma unroll 8
    for (int ts = 0; ts < ST; ++ts) M = fmaxf(M, m_part[b * ST + ts]);

    float L = 0.f;
    float4 acc = make_float4(0.f, 0.f, 0.f, 0.f);
    for (int ts = 0; ts < ST; ++ts) {
        const int pi = b * ST + ts;
        const float r = __expf(m_part[pi] - M);
        L += r * l_part[pi];
        const float4 v = ((const float4*)(o_part + (size_t)pi * EE))[tid];
        acc.x += r * v.x; acc.y += r * v.y; acc.z += r * v.z; acc.w += r * v.w;
    }
    const float inv = 1.f / L;
    acc.x *= inv; acc.y *= inv; acc.z *= inv; acc.w *= inv;
    ((float4*)(out + (size_t)b * EE))[tid] = acc;
}

extern "C" void kernel_launch(void* const* d_in, const int* in_sizes, int n_in,
                              void* d_out, int out_size, void* d_ws, size_t ws_size,
                              hipStream_t stream) {
    const float* x    = (const float*)d_in[0];  // (B,T,E)
    const float* c    = (const float*)d_in[1];  // (B,E)
    const float* W    = (const float*)d_in[2];  // (E,1)
    const float* bvec = (const float*)d_in[3];  // (T,1)
    const float* U    = (const float*)d_in[4];  // (E,T)
    float* out = (float*)d_out;                 // (B,E)

    float* ws     = (float*)d_ws;
    float* m_part = ws + M_OFF;
    float* l_part = ws + L_OFF;
    float* o_part = ws + O_OFF;

    k_fused<<<NBG * ST, 256, 0, stream>>>(x, c, W, bvec, U, m_part, l_part, o_part);
    k_merge<<<BB, 256, 0, stream>>>(m_part, l_part, o_part, out);
}